// Round 6
// baseline (386.701 us; speedup 1.0000x reference)
//
#include <hip/hip_runtime.h>
#include <cstddef>
#include <cstdint>

#define Tn 52
#define Fn 64
#define Hn 32
#define Bn 8192
#define XHAT_ELEMS (Bn * Tn * Fn)   // fp32 elems of x_hat == one packed-u32 [T,B,64] array
#define L2E 1.44269504088896340736f

typedef __attribute__((ext_vector_type(8))) short bf8v;        // 8 bf16 (4 VGPRs)
typedef __attribute__((ext_vector_type(4))) float f4v;         // 4 fp32 accum
typedef __attribute__((ext_vector_type(4))) unsigned int u4v;  // 4 packed hi|lo words

__device__ __forceinline__ f4v mfma_bf16(bf8v a, bf8v b, f4v c) {
    return __builtin_amdgcn_mfma_f32_16x16x32_bf16(a, b, c, 0, 0, 0);
}

// truncation split packed into one u32: v = hi + lo + O(2^-17 |v|)
__device__ __forceinline__ unsigned pack_hl(float v) {
    unsigned b  = __float_as_uint(v);
    unsigned hi = b & 0xFFFF0000u;
    float lf    = v - __uint_as_float(hi);
    return hi | (__float_as_uint(lf) >> 16);
}

__device__ __forceinline__ void split_tr(float v, unsigned short& hi, unsigned short& lo) {
    unsigned b = __float_as_uint(v);
    hi = (unsigned short)(b >> 16);
    float lf = v - __uint_as_float(b & 0xFFFF0000u);
    lo = (unsigned short)(__float_as_uint(lf) >> 16);
}

__device__ __forceinline__ void split8v(float4 a, float4 b, bf8v& h, bf8v& l) {
    float v[8] = {a.x, a.y, a.z, a.w, b.x, b.y, b.z, b.w};
#pragma unroll
    for (int j = 0; j < 8; ++j) {
        unsigned bb = __float_as_uint(v[j]);
        h[j] = (short)(bb >> 16);
        float lf = v[j] - __uint_as_float(bb & 0xFFFF0000u);
        l[j] = (short)(__float_as_uint(lf) >> 16);
    }
}

// 8 packed u32 -> hi/lo bf16 fragments via v_perm_b32
__device__ __forceinline__ void unpack8(u4v w0, u4v w1, bf8v& h, bf8v& l) {
    union { unsigned u[4]; bf8v v; } H, L;
#pragma unroll
    for (int k = 0; k < 2; ++k) {
        H.u[k]     = __builtin_amdgcn_perm(w0[2*k+1], w0[2*k], 0x07060302u);
        H.u[k + 2] = __builtin_amdgcn_perm(w1[2*k+1], w1[2*k], 0x07060302u);
        L.u[k]     = __builtin_amdgcn_perm(w0[2*k+1], w0[2*k], 0x05040100u);
        L.u[k + 2] = __builtin_amdgcn_perm(w1[2*k+1], w1[2*k], 0x05040100u);
    }
    h = H.v; l = L.v;
}

// barrier WITHOUT vmcnt drain: cross-wave data flows via LDS only.
__device__ __forceinline__ void lds_barrier() {
    __builtin_amdgcn_sched_barrier(0);
    asm volatile("s_waitcnt lgkmcnt(0)" ::: "memory");
    __builtin_amdgcn_s_barrier();
    __builtin_amdgcn_sched_barrier(0);
}

// Gates pre-scaled by log2e (g-gate by 2*log2e). One rcp for c2, one for h.
__device__ __forceinline__ float lstm_one(float aI, float aF, float aG, float aO, float& cst) {
    float ei = exp2f(fminf(40.f, -aI));
    float ef = exp2f(fminf(40.f, -aF));
    float eg = exp2f(fminf(40.f, -aG));
    float eo = exp2f(fminf(40.f, -aO));
    float p   = (1.f + ei) * (1.f + eg);
    float num = cst * p + (1.f - eg) * (1.f + ef);
    float den = (1.f + ef) * p;
    float c2  = num * __builtin_amdgcn_rcpf(den);
    cst = c2;
    float e2 = exp2f(fminf(40.f, -2.f * L2E * c2));
    return (1.f - e2) * __builtin_amdgcn_rcpf((1.f + eo) * (1.f + e2));
}

// split-3: acc += aL*Wh + aH*Wl + aH*Wh
#define GM3(ACC, AH, AL, WHx, WLx)   \
    ACC = mfma_bf16(AL, WHx, ACC);   \
    ACC = mfma_bf16(AH, WLx, ACC);   \
    ACC = mfma_bf16(AH, WHx, ACC);

// ---------------------------------------------------------------------------
// Prep: weights -> fragment-ordered bf16 hi/lo, pre-scaled by log2e
// (g-gate rows by 2*log2e). [grp][cell(4)][nt(8)][ki(3)][lane(64)][j(8)]
//   gate = nt*16 + (lane&15); k = ki*32 + (lane>>4)*8 + j
// ---------------------------------------------------------------------------
__global__ void prep_kernel(const float* __restrict__ eWih, const float* __restrict__ eWhh,
                            const float* __restrict__ dWih, const float* __restrict__ dWhh,
                            unsigned short* __restrict__ ws)
{
    int fid = blockIdx.x * 256 + threadIdx.x;
    if (fid >= 12288) return;
    int lane = fid & 63;
    int ki   = (fid >> 6) % 3;
    int nt   = (fid / 192) & 7;
    int cell = (fid / 1536) & 3;
    int grp  = fid / 6144;
    const float* Wih = grp ? dWih : eWih;
    const float* Whh = grp ? dWhh : eWhh;
    int gate = nt * 16 + (lane & 15);
    float scale = ((gate >> 5) == 2) ? 2.f * L2E : L2E;
    int k0 = ki * 32 + (lane >> 4) * 8;
    size_t base = (size_t)grp * 98304 + (size_t)cell * 12288 + nt * 1536 + ki * 512 + lane * 8;
#pragma unroll
    for (int j = 0; j < 8; ++j) {
        int k = k0 + j;
        float v = (k < 64) ? Wih[(size_t)cell * 8192 + gate * 64 + k]
                           : Whh[(size_t)cell * 4096 + gate * 32 + (k - 64)];
        v *= scale;
        split_tr(v, ws[base + j], ws[base + 49152 + j]);
    }
}

// ---------------------------------------------------------------------------
// Encoder: block = 256 thr = 4 AUTONOMOUS waves (dir x 16-row subgroup).
// grid 256 -> 1024 waves = 1024 SIMDs, 1 wave/SIMD, ~320 VGPR.
// Wave owns all 8 gate-tiles of its cell (192 weight VGPRs); h-exchange is
// wave-private LDS (lgkmcnt only) -> ZERO barriers in the time loop.
// ---------------------------------------------------------------------------
template<int IS_L0>
__global__ __launch_bounds__(256, 1)
void enc_kernel(const float* __restrict__ X, const unsigned* __restrict__ Xp,
                const float* __restrict__ h0, const float* __restrict__ c0,
                const unsigned short* __restrict__ Whi, const unsigned short* __restrict__ Wlo,
                const float* __restrict__ bias, int layer,
                unsigned* __restrict__ outp, float* __restrict__ z)
{
    __shared__ __align__(16) unsigned Hs[4][16][36];   // per-wave private h scratch
    const int tid = threadIdx.x, w = tid >> 6, lane = tid & 63;
    const int d = w & 1;
    const int a = lane & 15, kb = lane >> 4;
    const int row0 = blockIdx.x * 32 + (w >> 1) * 16;
    const int ci = 2 * layer + d;
    unsigned (*Hw)[36] = Hs[w];

    bf8v WH[8][3], WL[8][3];   // 48 frags = 192 VGPR, loaded once
#pragma unroll
    for (int nt = 0; nt < 8; ++nt)
#pragma unroll
        for (int ki = 0; ki < 3; ++ki) {
            size_t off = (size_t)ci * 12288 + nt * 1536 + ki * 512 + lane * 8;
            WH[nt][ki] = *(const bf8v*)(Whi + off);
            WL[nt][ki] = *(const bf8v*)(Wlo + off);
        }
    float bj[8];
#pragma unroll
    for (int nt = 0; nt < 8; ++nt)
        bj[nt] = bias[ci * 128 + nt * 16 + a] * (((nt >> 1) == 2) ? 2.f * L2E : L2E);

    float cst[2][4], hfin[2][4];
#pragma unroll
    for (int h = 0; h < 2; ++h)
#pragma unroll
        for (int j = 0; j < 4; ++j) {
            int r = row0 + 4 * kb + j, u = a + 16 * h;
            cst[h][j] = c0[((size_t)ci * Bn + r) * Hn + u];
            Hw[4 * kb + j][u] = pack_hl(h0[((size_t)ci * Bn + r) * Hn + u]);
        }
    // no barrier: Hw is wave-private; compiler orders via lgkmcnt

    const int grow = row0 + a;   // this lane's A-fragment row
    float4 p0, p1, p2, p3; u4v pw0, pw1, pw2, pw3;
    {
        int tt = d ? (Tn - 1) : 0;
        if (IS_L0) {
            const float* sp = X + ((size_t)grow * Tn + tt) * Fn;
            p0 = *(const float4*)(sp + kb * 8);      p1 = *(const float4*)(sp + kb * 8 + 4);
            p2 = *(const float4*)(sp + 32 + kb * 8); p3 = *(const float4*)(sp + 32 + kb * 8 + 4);
        } else {
            const unsigned* sp = Xp + ((size_t)tt * Bn + grow) * Fn;
            pw0 = *(const u4v*)(sp + kb * 8);      pw1 = *(const u4v*)(sp + kb * 8 + 4);
            pw2 = *(const u4v*)(sp + 32 + kb * 8); pw3 = *(const u4v*)(sp + 32 + kb * 8 + 4);
        }
    }

    for (int t = 0; t < Tn; ++t) {
        // issue h reads early (consumed after x-part MFMAs)
        u4v hw0 = *(const u4v*)&Hw[a][kb * 8];
        u4v hw1 = *(const u4v*)&Hw[a][kb * 8 + 4];
        bf8v xh0, xl0, xh1, xl1;
        if (IS_L0) { split8v(p0, p1, xh0, xl0); split8v(p2, p3, xh1, xl1); }
        else       { unpack8(pw0, pw1, xh0, xl0); unpack8(pw2, pw3, xh1, xl1); }
        {   // prefetch t+1
            int tn = (t + 1 < Tn) ? t + 1 : t;
            int tt = d ? (Tn - 1 - tn) : tn;
            if (IS_L0) {
                const float* sp = X + ((size_t)grow * Tn + tt) * Fn;
                p0 = *(const float4*)(sp + kb * 8);      p1 = *(const float4*)(sp + kb * 8 + 4);
                p2 = *(const float4*)(sp + 32 + kb * 8); p3 = *(const float4*)(sp + 32 + kb * 8 + 4);
            } else {
                const unsigned* sp = Xp + ((size_t)tt * Bn + grow) * Fn;
                pw0 = *(const u4v*)(sp + kb * 8);      pw1 = *(const u4v*)(sp + kb * 8 + 4);
                pw2 = *(const u4v*)(sp + 32 + kb * 8); pw3 = *(const u4v*)(sp + 32 + kb * 8 + 4);
            }
        }
        f4v acc[8];
#pragma unroll
        for (int nt = 0; nt < 8; ++nt) acc[nt] = (f4v){bj[nt], bj[nt], bj[nt], bj[nt]};
#pragma unroll
        for (int nt = 0; nt < 8; ++nt) { GM3(acc[nt], xh0, xl0, WH[nt][0], WL[nt][0]); }
#pragma unroll
        for (int nt = 0; nt < 8; ++nt) { GM3(acc[nt], xh1, xl1, WH[nt][1], WL[nt][1]); }
        bf8v hh, hl;
        unpack8(hw0, hw1, hh, hl);
#pragma unroll
        for (int nt = 0; nt < 8; ++nt) { GM3(acc[nt], hh, hl, WH[nt][2], WL[nt][2]); }
        int tp = d ? (Tn - 1 - t) : t;
#pragma unroll
        for (int h = 0; h < 2; ++h)
#pragma unroll
            for (int j = 0; j < 4; ++j) {
                float hv = lstm_one(acc[h][j], acc[2 + h][j], acc[4 + h][j], acc[6 + h][j],
                                    cst[h][j]);
                hfin[h][j] = hv;
                unsigned hp = pack_hl(hv);
                Hw[4 * kb + j][a + 16 * h] = hp;
                if (IS_L0)
                    outp[((size_t)tp * Bn + row0 + 4 * kb + j) * Fn + d * 32 + a + 16 * h] = hp;
            }
    }
#pragma unroll
    for (int h = 0; h < 2; ++h)
#pragma unroll
        for (int j = 0; j < 4; ++j) {
            size_t zr = (size_t)(row0 + 4 * kb + j) * 256;
            z[zr + ci * 32 + a + 16 * h]       = hfin[h][j];
            z[zr + 128 + ci * 32 + a + 16 * h] = cst[h][j];
        }
}

// ---------------------------------------------------------------------------
// Decoder: block = 256 thr = 4 waves (one per cell), 32 rows = 2 groups,
// grid 256 (1 block/CU, 1 wave/SIMD). Slot pipeline: A-waves (cells 0,1) on
// group g while B-waves (cells 2,3) on g^1 -> 2 barriers/step. h wave-private.
// ---------------------------------------------------------------------------
__global__ __launch_bounds__(256, 1)
void dec_kernel(const unsigned short* __restrict__ Whi, const unsigned short* __restrict__ Wlo,
                const float* __restrict__ bias, const float* __restrict__ z,
                float* __restrict__ xhat)
{
    __shared__ __align__(16) unsigned Ys[2][2][16][68];   // [grp][parity][row][feat]
    __shared__ __align__(16) unsigned Ms[2][16][68];      // [grp][row][feat]
    __shared__ __align__(16) unsigned Hs[4][2][16][36];   // [wave][grp][row][unit] private

    const int tid = threadIdx.x, w = tid >> 6, lane = tid & 63;
    const int P = w >> 1, cell = (P << 1) + (w & 1);
    const int a = lane & 15, kb = lane >> 4;
    const int row0 = blockIdx.x * 32;

    bf8v WH[8][3], WL[8][3];
#pragma unroll
    for (int nt = 0; nt < 8; ++nt)
#pragma unroll
        for (int ki = 0; ki < 3; ++ki) {
            size_t off = (size_t)cell * 12288 + nt * 1536 + ki * 512 + lane * 8;
            WH[nt][ki] = *(const bf8v*)(Whi + off);
            WL[nt][ki] = *(const bf8v*)(Wlo + off);
        }
    float bj[8];
#pragma unroll
    for (int nt = 0; nt < 8; ++nt)
        bj[nt] = bias[cell * 128 + nt * 16 + a] * (((nt >> 1) == 2) ? 2.f * L2E : L2E);

    float cst0[8], cst1[8];   // [h*4+j] per group
#pragma unroll
    for (int h = 0; h < 2; ++h)
#pragma unroll
        for (int j = 0; j < 4; ++j) {
            int u = a + 16 * h;
            int r0 = row0 + 4 * kb + j, r1 = r0 + 16;
            cst0[h * 4 + j] = z[(size_t)r0 * 256 + 128 + cell * 32 + u];
            cst1[h * 4 + j] = z[(size_t)r1 * 256 + 128 + cell * 32 + u];
            Hs[w][0][4 * kb + j][u] = pack_hl(z[(size_t)r0 * 256 + cell * 32 + u]);
            Hs[w][1][4 * kb + j][u] = pack_hl(z[(size_t)r1 * 256 + cell * 32 + u]);
        }

    auto cellstep = [&](int G, int t, bool isA, float (&cst)[8]) {
        u4v v0 = {}, v1 = {}, v2 = {}, v3 = {};
        const bool hasV = (!isA) || (t > 0);
        if (isA) {
            if (t > 0) {
                const unsigned (*Yr)[68] = Ys[G][(t - 1) & 1];
                v0 = *(const u4v*)&Yr[a][kb * 8];      v1 = *(const u4v*)&Yr[a][kb * 8 + 4];
                v2 = *(const u4v*)&Yr[a][32 + kb * 8]; v3 = *(const u4v*)&Yr[a][32 + kb * 8 + 4];
            }
        } else {
            const unsigned (*Mr)[68] = Ms[G];
            v0 = *(const u4v*)&Mr[a][kb * 8];      v1 = *(const u4v*)&Mr[a][kb * 8 + 4];
            v2 = *(const u4v*)&Mr[a][32 + kb * 8]; v3 = *(const u4v*)&Mr[a][32 + kb * 8 + 4];
        }
        u4v hw0 = *(const u4v*)&Hs[w][G][a][kb * 8];
        u4v hw1 = *(const u4v*)&Hs[w][G][a][kb * 8 + 4];
        f4v acc[8];
#pragma unroll
        for (int nt = 0; nt < 8; ++nt) acc[nt] = (f4v){bj[nt], bj[nt], bj[nt], bj[nt]};
        if (hasV) {
            bf8v a0, l0, a1, l1;
            unpack8(v0, v1, a0, l0);
            unpack8(v2, v3, a1, l1);
#pragma unroll
            for (int nt = 0; nt < 8; ++nt) { GM3(acc[nt], a0, l0, WH[nt][0], WL[nt][0]); }
#pragma unroll
            for (int nt = 0; nt < 8; ++nt) { GM3(acc[nt], a1, l1, WH[nt][1], WL[nt][1]); }
        }
        bf8v hh, hl;
        unpack8(hw0, hw1, hh, hl);
#pragma unroll
        for (int nt = 0; nt < 8; ++nt) { GM3(acc[nt], hh, hl, WH[nt][2], WL[nt][2]); }
#pragma unroll
        for (int h = 0; h < 2; ++h)
#pragma unroll
            for (int j = 0; j < 4; ++j) {
                float hv = lstm_one(acc[h][j], acc[2 + h][j], acc[4 + h][j], acc[6 + h][j],
                                    cst[h * 4 + j]);
                unsigned hp = pack_hl(hv);
                int u = a + 16 * h, r = 4 * kb + j;
                Hs[w][G][r][u] = hp;
                if (isA) {
                    Ms[G][r][cell * 32 + u] = hp;
                } else {
                    Ys[G][t & 1][r][(cell - 2) * 32 + u] = hp;
                    xhat[((size_t)(row0 + G * 16 + r) * Tn + t) * Fn + (cell - 2) * 32 + u] = hv;
                }
            }
    };

    for (int t = 0; t < Tn; ++t) {
        // slot even: A on G0(t), B on G1(t-1)
        if (P == 0)      cellstep(0, t, true, cst0);
        else if (t > 0)  cellstep(1, t - 1, false, cst1);
        lds_barrier();
        // slot odd: A on G1(t), B on G0(t)
        if (P == 0)      cellstep(1, t, true, cst1);
        else             cellstep(0, t, false, cst0);
        lds_barrier();
    }
    if (P == 1) cellstep(1, Tn - 1, false, cst1);   // epilogue: G1 last step
}

extern "C" void kernel_launch(void* const* d_in, const int* in_sizes, int n_in,
                              void* d_out, int out_size, void* d_ws, size_t ws_size,
                              hipStream_t stream) {
    const float* x    = (const float*)d_in[0];
    const float* h0   = (const float*)d_in[1];
    const float* c0   = (const float*)d_in[2];
    const float* eWih = (const float*)d_in[3];
    const float* eWhh = (const float*)d_in[4];
    const float* eb   = (const float*)d_in[5];
    const float* dWih = (const float*)d_in[6];
    const float* dWhh = (const float*)d_in[7];
    const float* db   = (const float*)d_in[8];

    float* out = (float*)d_out;
    unsigned* xs1p = (unsigned*)d_out;               // [T,B,64] packed hi|lo, == x_hat bytes
    float* zb = out + (size_t)XHAT_ELEMS;            // [B,256] latent
    unsigned short* wsb = (unsigned short*)d_ws;     // 384 KB weight fragments

    hipLaunchKernelGGL(prep_kernel, dim3(48), dim3(256), 0, stream,
                       eWih, eWhh, dWih, dWhh, wsb);
    // encoder layer 0: x -> xs1 (packed) + z slots 0,1
    hipLaunchKernelGGL((enc_kernel<1>), dim3(Bn / 32), dim3(256), 0, stream,
                       x, (const unsigned*)nullptr, h0, c0,
                       wsb, wsb + 49152, eb, 0, xs1p, zb);
    // encoder layer 1: xs1 -> z slots 2,3
    hipLaunchKernelGGL((enc_kernel<0>), dim3(Bn / 32), dim3(256), 0, stream,
                       (const float*)nullptr, xs1p, h0, c0,
                       wsb, wsb + 49152, eb, 1, (unsigned*)nullptr, zb);
    // decoder: z -> x_hat (overwrites xs1 region)
    hipLaunchKernelGGL(dec_kernel, dim3(Bn / 32), dim3(256), 0, stream,
                       wsb + 98304, wsb + 147456, db, zb, out);
}

// Round 7
// 316.649 us; speedup vs baseline: 1.2212x; 1.2212x over previous
//
#include <hip/hip_runtime.h>
#include <cstddef>
#include <cstdint>

#define Tn 52
#define Fn 64
#define Hn 32
#define Bn 8192
#define XHAT_ELEMS (Bn * Tn * Fn)   // fp32 elems of x_hat == 2 bf16 [T,B,64] planes
#define L2E 1.44269504088896340736f

typedef __attribute__((ext_vector_type(8))) short bf8v;   // 8 bf16 (4 VGPRs)
typedef __attribute__((ext_vector_type(4))) float f4v;    // 4 fp32 accum

__device__ __forceinline__ f4v mfma_bf16(bf8v a, bf8v b, f4v c) {
    return __builtin_amdgcn_mfma_f32_16x16x32_bf16(a, b, c, 0, 0, 0);
}

// exact truncation split of activations: v = hi + lo + O(2^-17 |v|)
__device__ __forceinline__ void split_tr(float v, unsigned short& hi, unsigned short& lo) {
    unsigned b = __float_as_uint(v);
    hi = (unsigned short)(b >> 16);
    float lf = v - __uint_as_float(b & 0xFFFF0000u);
    lo = (unsigned short)(__float_as_uint(lf) >> 16);
}

__device__ __forceinline__ void split8v(float4 a, float4 b, bf8v& h, bf8v& l) {
    float v[8] = {a.x, a.y, a.z, a.w, b.x, b.y, b.z, b.w};
#pragma unroll
    for (int j = 0; j < 8; ++j) {
        unsigned bb = __float_as_uint(v[j]);
        h[j] = (short)(bb >> 16);
        float lf = v[j] - __uint_as_float(bb & 0xFFFF0000u);
        l[j] = (short)(__float_as_uint(lf) >> 16);
    }
}

// RNE round to bf16 (for weights; unbiased, unlike truncation)
__device__ __forceinline__ unsigned short rne_bf16(float v) {
    unsigned b = __float_as_uint(v);
    unsigned r = ((b >> 16) & 1u) + 0x7FFFu;
    return (unsigned short)((b + r) >> 16);
}

// barrier WITHOUT vmcnt drain: cross-wave data flows via LDS only.
__device__ __forceinline__ void lds_barrier() {
    __builtin_amdgcn_sched_barrier(0);
    asm volatile("s_waitcnt lgkmcnt(0)" ::: "memory");
    __builtin_amdgcn_s_barrier();
    __builtin_amdgcn_sched_barrier(0);
}

// Gates pre-scaled by log2e (g-gate by 2*log2e). One rcp for c2, one for h.
__device__ __forceinline__ float lstm_one(float aI, float aF, float aG, float aO, float& cst) {
    float ei = exp2f(fminf(40.f, -aI));
    float ef = exp2f(fminf(40.f, -aF));
    float eg = exp2f(fminf(40.f, -aG));
    float eo = exp2f(fminf(40.f, -aO));
    float p   = (1.f + ei) * (1.f + eg);
    float num = cst * p + (1.f - eg) * (1.f + ef);
    float den = (1.f + ef) * p;
    float c2  = num * __builtin_amdgcn_rcpf(den);
    cst = c2;
    float e2 = exp2f(fminf(40.f, -2.f * L2E * c2));
    return (1.f - e2) * __builtin_amdgcn_rcpf((1.f + eo) * (1.f + e2));
}

// split-2: acc += aL*WH + aH*WH (weights RNE bf16; activation split exact)
#define GM2(ACC, AH, AL, WHx)        \
    ACC = mfma_bf16(AL, WHx, ACC);   \
    ACC = mfma_bf16(AH, WHx, ACC);

// pin the 12 weight fragments live across the loop (defeats remat/reload)
#define PINW(W)                                                               \
    asm volatile("" : "+v"(W[0][0]), "+v"(W[0][1]), "+v"(W[0][2]),            \
                      "+v"(W[1][0]), "+v"(W[1][1]), "+v"(W[1][2]));           \
    asm volatile("" : "+v"(W[2][0]), "+v"(W[2][1]), "+v"(W[2][2]),            \
                      "+v"(W[3][0]), "+v"(W[3][1]), "+v"(W[3][2]));

// ---------------------------------------------------------------------------
// Prep: weights -> fragment-ordered RNE bf16, pre-scaled by log2e
// (g-gate rows by 2*log2e). [grp][cell(4)][nt(8)][ki(3)][lane(64)][j(8)]
//   gate = nt*16 + (lane&15); k = ki*32 + (lane>>4)*8 + j
// ---------------------------------------------------------------------------
__global__ void prep_kernel(const float* __restrict__ eWih, const float* __restrict__ eWhh,
                            const float* __restrict__ dWih, const float* __restrict__ dWhh,
                            unsigned short* __restrict__ ws)
{
    int fid = blockIdx.x * 256 + threadIdx.x;
    if (fid >= 12288) return;
    int lane = fid & 63;
    int ki   = (fid >> 6) % 3;
    int nt   = (fid / 192) & 7;
    int cell = (fid / 1536) & 3;
    int grp  = fid / 6144;
    const float* Wih = grp ? dWih : eWih;
    const float* Whh = grp ? dWhh : eWhh;
    int gate = nt * 16 + (lane & 15);
    float scale = ((gate >> 5) == 2) ? 2.f * L2E : L2E;
    int k0 = ki * 32 + (lane >> 4) * 8;
    size_t base = (size_t)grp * 98304 + (size_t)cell * 12288 + nt * 1536 + ki * 512 + lane * 8;
#pragma unroll
    for (int j = 0; j < 8; ++j) {
        int k = k0 + j;
        float v = (k < 64) ? Wih[(size_t)cell * 8192 + gate * 64 + k]
                           : Whh[(size_t)cell * 4096 + gate * 32 + (k - 64)];
        ws[base + j] = rne_bf16(v * scale);
    }
}

// ---------------------------------------------------------------------------
// Encoder layer: block = 256 thr (4 waves = dir x q-half), 16 rows, grid 512
// -> 2 blocks/CU. In-register combine; 1 barrier/step; weights VGPR-pinned.
// h exchange via separate hi/lo bf16 planes (no unpack perms).
// ---------------------------------------------------------------------------
template<int IS_L0>
__global__ __launch_bounds__(256, 2)
void enc_kernel(const float* __restrict__ X,
                const unsigned short* __restrict__ Xh, const unsigned short* __restrict__ Xl,
                const float* __restrict__ h0, const float* __restrict__ c0,
                const unsigned short* __restrict__ Whi, const float* __restrict__ bias,
                int layer,
                unsigned short* __restrict__ outh, unsigned short* __restrict__ outl,
                float* __restrict__ z)
{
    __shared__ __align__(16) unsigned short Hsh[2][2][16][40], Hsl[2][2][16][40];
    const int tid = threadIdx.x, w = tid >> 6, lane = tid & 63;
    const int d = w >> 1, q = w & 1;
    const int a = lane & 15, kb = lane >> 4;
    const int u = q * 16 + a;
    const int row0 = blockIdx.x * 16;
    const int ci = 2 * layer + d;

    bf8v WH[4][3];   // 12 frags = 48 VGPR, pinned resident
#pragma unroll
    for (int g = 0; g < 4; ++g)
#pragma unroll
        for (int ki = 0; ki < 3; ++ki)
            WH[g][ki] = *(const bf8v*)(Whi + (size_t)ci * 12288 + (2 * g + q) * 1536
                                       + ki * 512 + lane * 8);
    float bj[4];
#pragma unroll
    for (int g = 0; g < 4; ++g)
        bj[g] = bias[ci * 128 + g * 32 + u] * ((g == 2) ? 2.f * L2E : L2E);
    float cst[4], hfin[4];
#pragma unroll
    for (int j = 0; j < 4; ++j)
        cst[j] = c0[((size_t)ci * Bn + row0 + 4 * kb + j) * Hn + u];

    {   // h0 -> parity-1: 2 dirs x 16 rows x 32 units / 256 thr = 4 each
        int dd = tid >> 7, rr = (tid >> 3) & 15, u4 = (tid & 7) * 4;
        const float* src = h0 + ((size_t)(2 * layer + dd) * Bn + row0 + rr) * Hn + u4;
#pragma unroll
        for (int e = 0; e < 4; ++e)
            split_tr(src[e], Hsh[dd][1][rr][u4 + e], Hsl[dd][1][rr][u4 + e]);
    }
    __syncthreads();

    const int grow = row0 + a;   // this lane's A-fragment row
    float4 p0, p1, p2, p3; bf8v ph0, pl0, ph1, pl1;
    {
        int tt = d ? (Tn - 1) : 0;
        if (IS_L0) {
            const float* sp = X + ((size_t)grow * Tn + tt) * Fn;
            p0 = *(const float4*)(sp + kb * 8);      p1 = *(const float4*)(sp + kb * 8 + 4);
            p2 = *(const float4*)(sp + 32 + kb * 8); p3 = *(const float4*)(sp + 32 + kb * 8 + 4);
        } else {
            size_t so = ((size_t)tt * Bn + grow) * Fn + kb * 8;
            ph0 = *(const bf8v*)(Xh + so);      pl0 = *(const bf8v*)(Xl + so);
            ph1 = *(const bf8v*)(Xh + so + 32); pl1 = *(const bf8v*)(Xl + so + 32);
        }
    }

    for (int t = 0; t < Tn; ++t) {
        PINW(WH);
        bf8v xh0, xl0, xh1, xl1;
        if (IS_L0) { split8v(p0, p1, xh0, xl0); split8v(p2, p3, xh1, xl1); }
        else       { xh0 = ph0; xl0 = pl0; xh1 = ph1; xl1 = pl1; }
        {   // prefetch t+1
            int tn = (t + 1 < Tn) ? t + 1 : t;
            int tt = d ? (Tn - 1 - tn) : tn;
            if (IS_L0) {
                const float* sp = X + ((size_t)grow * Tn + tt) * Fn;
                p0 = *(const float4*)(sp + kb * 8);      p1 = *(const float4*)(sp + kb * 8 + 4);
                p2 = *(const float4*)(sp + 32 + kb * 8); p3 = *(const float4*)(sp + 32 + kb * 8 + 4);
            } else {
                size_t so = ((size_t)tt * Bn + grow) * Fn + kb * 8;
                ph0 = *(const bf8v*)(Xh + so);      pl0 = *(const bf8v*)(Xl + so);
                ph1 = *(const bf8v*)(Xh + so + 32); pl1 = *(const bf8v*)(Xl + so + 32);
            }
        }
        bf8v hh = *(const bf8v*)&Hsh[d][(t & 1) ^ 1][a][kb * 8];
        bf8v hl = *(const bf8v*)&Hsl[d][(t & 1) ^ 1][a][kb * 8];
        f4v acc[4];
#pragma unroll
        for (int g = 0; g < 4; ++g) acc[g] = (f4v){bj[g], bj[g], bj[g], bj[g]};
#pragma unroll
        for (int g = 0; g < 4; ++g) { GM2(acc[g], xh0, xl0, WH[g][0]); }
#pragma unroll
        for (int g = 0; g < 4; ++g) { GM2(acc[g], xh1, xl1, WH[g][1]); }
#pragma unroll
        for (int g = 0; g < 4; ++g) { GM2(acc[g], hh, hl, WH[g][2]); }
        int tp = d ? (Tn - 1 - t) : t;
#pragma unroll
        for (int j = 0; j < 4; ++j) {
            float hv = lstm_one(acc[0][j], acc[1][j], acc[2][j], acc[3][j], cst[j]);
            hfin[j] = hv;
            unsigned short hi_, lo_;
            split_tr(hv, hi_, lo_);
            Hsh[d][t & 1][4 * kb + j][u] = hi_;
            Hsl[d][t & 1][4 * kb + j][u] = lo_;
            if (IS_L0) {
                size_t o = ((size_t)tp * Bn + row0 + 4 * kb + j) * Fn + d * 32 + u;
                outh[o] = hi_;
                outl[o] = lo_;
            }
        }
        lds_barrier();
    }
#pragma unroll
    for (int j = 0; j < 4; ++j) {
        size_t zr = (size_t)(row0 + 4 * kb + j) * 256;
        z[zr + ci * 32 + u]       = hfin[j];
        z[zr + 128 + ci * 32 + u] = cst[j];
    }
}

// ---------------------------------------------------------------------------
// Decoder: block = 512 thr (8 waves: P x cell x q-half), 32 rows = 2 groups,
// grid 256. Slot pipeline: A (cells 0,1) on group g, B (cells 2,3) on g^1.
// Weights VGPR-pinned; separate hi/lo planes for y/m/h (no perms).
// ---------------------------------------------------------------------------
__global__ __launch_bounds__(512, 2)
void dec_kernel(const unsigned short* __restrict__ Whi, const float* __restrict__ bias,
                const float* __restrict__ z, float* __restrict__ xhat)
{
    __shared__ __align__(16) unsigned short Ysh[2][2][16][72], Ysl[2][2][16][72];
    __shared__ __align__(16) unsigned short Msh[2][16][72],    Msl[2][16][72];
    __shared__ __align__(16) unsigned short Hsh[4][2][2][16][40], Hsl[4][2][2][16][40];

    const int tid = threadIdx.x, w = tid >> 6, lane = tid & 63;
    const int P = w >> 2, cl = (w >> 1) & 1, q = w & 1;
    const int cell = P * 2 + cl;
    const int a = lane & 15, kb = lane >> 4, u = q * 16 + a;
    const int row0 = blockIdx.x * 32;

    bf8v WH[4][3];   // 12 frags = 48 VGPR, pinned resident
#pragma unroll
    for (int g = 0; g < 4; ++g)
#pragma unroll
        for (int ki = 0; ki < 3; ++ki)
            WH[g][ki] = *(const bf8v*)(Whi + (size_t)cell * 12288 + (2 * g + q) * 1536
                                       + ki * 512 + lane * 8);
    float bj[4];
#pragma unroll
    for (int g = 0; g < 4; ++g)
        bj[g] = bias[cell * 128 + g * 32 + u] * ((g == 2) ? 2.f * L2E : L2E);

    float cst[2][4];   // [group][j]
#pragma unroll
    for (int G = 0; G < 2; ++G)
#pragma unroll
        for (int j = 0; j < 4; ++j)
            cst[G][j] = z[(size_t)(row0 + G * 16 + 4 * kb + j) * 256 + 128 + cell * 32 + u];

    {   // h-init -> parity-1: 4 cells x 32 rows x 32 units / 512 thr = 8 each
        int ct = tid >> 7, rem = tid & 127, rr = rem >> 2, u8 = (rem & 3) * 8;
        const float* src = z + (size_t)(row0 + rr) * 256 + ct * 32 + u8;
#pragma unroll
        for (int e = 0; e < 8; ++e)
            split_tr(src[e], Hsh[ct][rr >> 4][1][rr & 15][u8 + e],
                             Hsl[ct][rr >> 4][1][rr & 15][u8 + e]);
    }
    for (int i = tid; i < 2 * 16 * 72; i += 512) {   // y(-1)=0 at parity 1
        int G = (i >= 16 * 72) ? 1 : 0, rI = i - G * (16 * 72);
        Ysh[G][1][rI / 72][rI % 72] = 0;
        Ysl[G][1][rI / 72][rI % 72] = 0;
    }
    __syncthreads();

    auto cellstep = [&](int G, int t, bool isA) {
        const int par = t & 1, rpar = par ^ 1;
        f4v acc[4];
#pragma unroll
        for (int g = 0; g < 4; ++g) acc[g] = (f4v){bj[g], bj[g], bj[g], bj[g]};
        if (!isA || t > 0) {
            const unsigned short (*Vh)[72] = isA ? Ysh[G][rpar] : Msh[G];
            const unsigned short (*Vl)[72] = isA ? Ysl[G][rpar] : Msl[G];
            bf8v vh0 = *(const bf8v*)&Vh[a][kb * 8];
            bf8v vl0 = *(const bf8v*)&Vl[a][kb * 8];
            bf8v vh1 = *(const bf8v*)&Vh[a][32 + kb * 8];
            bf8v vl1 = *(const bf8v*)&Vl[a][32 + kb * 8];
#pragma unroll
            for (int g = 0; g < 4; ++g) { GM2(acc[g], vh0, vl0, WH[g][0]); }
#pragma unroll
            for (int g = 0; g < 4; ++g) { GM2(acc[g], vh1, vl1, WH[g][1]); }
        }
        bf8v hh = *(const bf8v*)&Hsh[cell][G][rpar][a][kb * 8];
        bf8v hl = *(const bf8v*)&Hsl[cell][G][rpar][a][kb * 8];
#pragma unroll
        for (int g = 0; g < 4; ++g) { GM2(acc[g], hh, hl, WH[g][2]); }
#pragma unroll
        for (int j = 0; j < 4; ++j) {
            float hv = lstm_one(acc[0][j], acc[1][j], acc[2][j], acc[3][j], cst[G][j]);
            unsigned short hi_, lo_;
            split_tr(hv, hi_, lo_);
            int r = 4 * kb + j;
            Hsh[cell][G][par][r][u] = hi_;
            Hsl[cell][G][par][r][u] = lo_;
            if (isA) {
                Msh[G][r][cl * 32 + u] = hi_;
                Msl[G][r][cl * 32 + u] = lo_;
            } else {
                Ysh[G][par][r][cl * 32 + u] = hi_;
                Ysl[G][par][r][cl * 32 + u] = lo_;
                xhat[((size_t)(row0 + G * 16 + r) * Tn + t) * Fn + cl * 32 + u] = hv;
            }
        }
    };

    for (int t = 0; t < Tn; ++t) {
        PINW(WH);
        // slot even: A on G0(t), B on G1(t-1)
        if (P == 0)      cellstep(0, t, true);
        else if (t > 0)  cellstep(1, t - 1, false);
        lds_barrier();
        // slot odd: A on G1(t), B on G0(t)
        if (P == 0)      cellstep(1, t, true);
        else             cellstep(0, t, false);
        lds_barrier();
    }
    if (P == 1) cellstep(1, Tn - 1, false);   // epilogue: G1 last step
}

extern "C" void kernel_launch(void* const* d_in, const int* in_sizes, int n_in,
                              void* d_out, int out_size, void* d_ws, size_t ws_size,
                              hipStream_t stream) {
    const float* x    = (const float*)d_in[0];
    const float* h0   = (const float*)d_in[1];
    const float* c0   = (const float*)d_in[2];
    const float* eWih = (const float*)d_in[3];
    const float* eWhh = (const float*)d_in[4];
    const float* eb   = (const float*)d_in[5];
    const float* dWih = (const float*)d_in[6];
    const float* dWhh = (const float*)d_in[7];
    const float* db   = (const float*)d_in[8];

    float* out = (float*)d_out;
    unsigned short* xs1h = (unsigned short*)d_out;          // [T,B,64] bf16 hi plane
    unsigned short* xs1l = xs1h + (size_t)XHAT_ELEMS;       // [T,B,64] bf16 lo plane
    float* zb = out + (size_t)XHAT_ELEMS;                   // [B,256] latent
    unsigned short* wsb = (unsigned short*)d_ws;            // weight fragments

    hipLaunchKernelGGL(prep_kernel, dim3(48), dim3(256), 0, stream,
                       eWih, eWhh, dWih, dWhh, wsb);
    // encoder layer 0: x -> xs1 planes + z slots 0,1
    hipLaunchKernelGGL((enc_kernel<1>), dim3(Bn / 16), dim3(256), 0, stream,
                       x, (const unsigned short*)nullptr, (const unsigned short*)nullptr,
                       h0, c0, wsb, eb, 0, xs1h, xs1l, zb);
    // encoder layer 1: xs1 planes -> z slots 2,3
    hipLaunchKernelGGL((enc_kernel<0>), dim3(Bn / 16), dim3(256), 0, stream,
                       (const float*)nullptr, xs1h, xs1l,
                       h0, c0, wsb, eb, 1,
                       (unsigned short*)nullptr, (unsigned short*)nullptr, zb);
    // decoder: z -> x_hat (overwrites xs1 region)
    hipLaunchKernelGGL(dec_kernel, dim3(Bn / 32), dim3(512), 0, stream,
                       wsb + 98304, db, zb, out);
}

// Round 8
// 267.647 us; speedup vs baseline: 1.4448x; 1.1831x over previous
//
#include <hip/hip_runtime.h>
#include <cstddef>
#include <cstdint>

#define Tn 52
#define Fn 64
#define Hn 32
#define Bn 8192
#define XHAT_ELEMS (Bn * Tn * Fn)   // fp32 elems of x_hat; xs1 bf16 plane fits in half
#define L2E 1.44269504088896340736f

typedef __attribute__((ext_vector_type(8))) short bf8v;   // 8 bf16 (4 VGPRs)
typedef __attribute__((ext_vector_type(4))) float f4v;    // 4 fp32 accum

__device__ __forceinline__ f4v mfma_bf16(bf8v a, bf8v b, f4v c) {
    return __builtin_amdgcn_mfma_f32_16x16x32_bf16(a, b, c, 0, 0, 0);
}

// RNE round to bf16
__device__ __forceinline__ unsigned short rne_bf16(float v) {
    unsigned b = __float_as_uint(v);
    unsigned r = ((b >> 16) & 1u) + 0x7FFFu;
    return (unsigned short)((b + r) >> 16);
}

__device__ __forceinline__ bf8v rne8(float4 a, float4 b) {
    float v[8] = {a.x, a.y, a.z, a.w, b.x, b.y, b.z, b.w};
    bf8v r;
#pragma unroll
    for (int j = 0; j < 8; ++j) r[j] = (short)rne_bf16(v[j]);
    return r;
}

// barrier WITHOUT vmcnt drain: cross-wave data flows via LDS only.
__device__ __forceinline__ void lds_barrier() {
    __builtin_amdgcn_sched_barrier(0);
    asm volatile("s_waitcnt lgkmcnt(0)" ::: "memory");
    __builtin_amdgcn_s_barrier();
    __builtin_amdgcn_sched_barrier(0);
}

// Gates pre-scaled by log2e (g-gate by 2*log2e). One rcp for c2, one for h.
__device__ __forceinline__ float lstm_one(float aI, float aF, float aG, float aO, float& cst) {
    float ei = exp2f(fminf(40.f, -aI));
    float ef = exp2f(fminf(40.f, -aF));
    float eg = exp2f(fminf(40.f, -aG));
    float eo = exp2f(fminf(40.f, -aO));
    float p   = (1.f + ei) * (1.f + eg);
    float num = cst * p + (1.f - eg) * (1.f + ef);
    float den = (1.f + ef) * p;
    float c2  = num * __builtin_amdgcn_rcpf(den);
    cst = c2;
    float e2 = exp2f(fminf(40.f, -2.f * L2E * c2));
    return (1.f - e2) * __builtin_amdgcn_rcpf((1.f + eo) * (1.f + e2));
}

// pin the 12 weight fragments live across the loop (defeats remat/reload)
#define PINW(W)                                                               \
    asm volatile("" : "+v"(W[0][0]), "+v"(W[0][1]), "+v"(W[0][2]),            \
                      "+v"(W[1][0]), "+v"(W[1][1]), "+v"(W[1][2]));           \
    asm volatile("" : "+v"(W[2][0]), "+v"(W[2][1]), "+v"(W[2][2]),            \
                      "+v"(W[3][0]), "+v"(W[3][1]), "+v"(W[3][2]));

// ---------------------------------------------------------------------------
// Prep: weights -> fragment-ordered RNE bf16, pre-scaled by log2e
// (g-gate rows by 2*log2e). [grp][cell(4)][nt(8)][ki(3)][lane(64)][j(8)]
//   gate = nt*16 + (lane&15); k = ki*32 + (lane>>4)*8 + j
// ---------------------------------------------------------------------------
__global__ void prep_kernel(const float* __restrict__ eWih, const float* __restrict__ eWhh,
                            const float* __restrict__ dWih, const float* __restrict__ dWhh,
                            unsigned short* __restrict__ ws)
{
    int fid = blockIdx.x * 256 + threadIdx.x;
    if (fid >= 12288) return;
    int lane = fid & 63;
    int ki   = (fid >> 6) % 3;
    int nt   = (fid / 192) & 7;
    int cell = (fid / 1536) & 3;
    int grp  = fid / 6144;
    const float* Wih = grp ? dWih : eWih;
    const float* Whh = grp ? dWhh : eWhh;
    int gate = nt * 16 + (lane & 15);
    float scale = ((gate >> 5) == 2) ? 2.f * L2E : L2E;
    int k0 = ki * 32 + (lane >> 4) * 8;
    size_t base = (size_t)grp * 98304 + (size_t)cell * 12288 + nt * 1536 + ki * 512 + lane * 8;
#pragma unroll
    for (int j = 0; j < 8; ++j) {
        int k = k0 + j;
        float v = (k < 64) ? Wih[(size_t)cell * 8192 + gate * 64 + k]
                           : Whh[(size_t)cell * 4096 + gate * 32 + (k - 64)];
        ws[base + j] = rne_bf16(v * scale);
    }
}

// ---------------------------------------------------------------------------
// Encoder layer: block = 256 thr (4 waves = dir x q-half), 16 rows, grid 512.
// Single-bf16 activations; x-part MFMAs of step t+1 hoisted BEFORE the
// barrier (post-barrier path = h-read -> 4 MFMA -> lstm -> write).
// ---------------------------------------------------------------------------
template<int IS_L0>
__global__ __launch_bounds__(256, 2)
void enc_kernel(const float* __restrict__ X, const unsigned short* __restrict__ Xh,
                const float* __restrict__ h0, const float* __restrict__ c0,
                const unsigned short* __restrict__ Whi, const float* __restrict__ bias,
                int layer, unsigned short* __restrict__ outh, float* __restrict__ z)
{
    __shared__ __align__(16) unsigned short Hsh[2][2][16][40];   // [dir][parity][row][unit]
    const int tid = threadIdx.x, w = tid >> 6, lane = tid & 63;
    const int d = w >> 1, q = w & 1;
    const int a = lane & 15, kb = lane >> 4;
    const int u = q * 16 + a;
    const int row0 = blockIdx.x * 16;
    const int ci = 2 * layer + d;

    bf8v WH[4][3];   // 12 frags = 48 VGPR, pinned
#pragma unroll
    for (int g = 0; g < 4; ++g)
#pragma unroll
        for (int ki = 0; ki < 3; ++ki)
            WH[g][ki] = *(const bf8v*)(Whi + (size_t)ci * 12288 + (2 * g + q) * 1536
                                       + ki * 512 + lane * 8);
    float bj[4];
#pragma unroll
    for (int g = 0; g < 4; ++g)
        bj[g] = bias[ci * 128 + g * 32 + u] * ((g == 2) ? 2.f * L2E : L2E);
    float cst[4], hfin[4];
#pragma unroll
    for (int j = 0; j < 4; ++j)
        cst[j] = c0[((size_t)ci * Bn + row0 + 4 * kb + j) * Hn + u];

    {   // h0 -> parity-1: 2 dirs x 16 rows x 32 units / 256 thr = 4 each
        int dd = tid >> 7, rr = (tid >> 3) & 15, u4 = (tid & 7) * 4;
        const float* src = h0 + ((size_t)(2 * layer + dd) * Bn + row0 + rr) * Hn + u4;
#pragma unroll
        for (int e = 0; e < 4; ++e)
            Hsh[dd][1][rr][u4 + e] = rne_bf16(src[e]);
    }
    __syncthreads();

    const int grow = row0 + a;   // this lane's A-fragment row
    float4 p0, p1, p2, p3; bf8v ph0, ph1;
    f4v acc[4];
    {   // t = 0: load x, build acc = bias + x-part; prefetch t = 1
        int tt = d ? (Tn - 1) : 0;
        bf8v xf0, xf1;
        if (IS_L0) {
            const float* sp = X + ((size_t)grow * Tn + tt) * Fn;
            xf0 = rne8(*(const float4*)(sp + kb * 8), *(const float4*)(sp + kb * 8 + 4));
            xf1 = rne8(*(const float4*)(sp + 32 + kb * 8), *(const float4*)(sp + 32 + kb * 8 + 4));
        } else {
            size_t so = ((size_t)tt * Bn + grow) * Fn + kb * 8;
            xf0 = *(const bf8v*)(Xh + so);
            xf1 = *(const bf8v*)(Xh + so + 32);
        }
#pragma unroll
        for (int g = 0; g < 4; ++g) {
            acc[g] = (f4v){bj[g], bj[g], bj[g], bj[g]};
            acc[g] = mfma_bf16(xf0, WH[g][0], acc[g]);
            acc[g] = mfma_bf16(xf1, WH[g][1], acc[g]);
        }
        int tt1 = d ? (Tn - 2) : 1;
        if (IS_L0) {
            const float* sp = X + ((size_t)grow * Tn + tt1) * Fn;
            p0 = *(const float4*)(sp + kb * 8);      p1 = *(const float4*)(sp + kb * 8 + 4);
            p2 = *(const float4*)(sp + 32 + kb * 8); p3 = *(const float4*)(sp + 32 + kb * 8 + 4);
        } else {
            size_t so = ((size_t)tt1 * Bn + grow) * Fn + kb * 8;
            ph0 = *(const bf8v*)(Xh + so);
            ph1 = *(const bf8v*)(Xh + so + 32);
        }
    }

    for (int t = 0; t < Tn; ++t) {
        PINW(WH);
        // post-barrier critical path: h-read -> 4 MFMA -> lstm -> write
        bf8v hh = *(const bf8v*)&Hsh[d][(t & 1) ^ 1][a][kb * 8];
#pragma unroll
        for (int g = 0; g < 4; ++g) acc[g] = mfma_bf16(hh, WH[g][2], acc[g]);
        int tp = d ? (Tn - 1 - t) : t;
#pragma unroll
        for (int j = 0; j < 4; ++j) {
            float hv = lstm_one(acc[0][j], acc[1][j], acc[2][j], acc[3][j], cst[j]);
            hfin[j] = hv;
            unsigned short hp = rne_bf16(hv);
            Hsh[d][t & 1][4 * kb + j][u] = hp;
            if (IS_L0)
                outh[((size_t)tp * Bn + row0 + 4 * kb + j) * Fn + d * 32 + u] = hp;
        }
        // pre-barrier: x-part of t+1 + prefetch t+2 (independent of h)
        {
            bf8v xf0, xf1;
            if (IS_L0) { xf0 = rne8(p0, p1); xf1 = rne8(p2, p3); }
            else       { xf0 = ph0; xf1 = ph1; }
#pragma unroll
            for (int g = 0; g < 4; ++g) {
                f4v t0 = (f4v){bj[g], bj[g], bj[g], bj[g]};
                t0 = mfma_bf16(xf0, WH[g][0], t0);
                acc[g] = mfma_bf16(xf1, WH[g][1], t0);
            }
            int ts = (t + 2 < Tn) ? t + 2 : Tn - 1;
            int tt = d ? (Tn - 1 - ts) : ts;
            if (IS_L0) {
                const float* sp = X + ((size_t)grow * Tn + tt) * Fn;
                p0 = *(const float4*)(sp + kb * 8);      p1 = *(const float4*)(sp + kb * 8 + 4);
                p2 = *(const float4*)(sp + 32 + kb * 8); p3 = *(const float4*)(sp + 32 + kb * 8 + 4);
            } else {
                size_t so = ((size_t)tt * Bn + grow) * Fn + kb * 8;
                ph0 = *(const bf8v*)(Xh + so);
                ph1 = *(const bf8v*)(Xh + so + 32);
            }
        }
        lds_barrier();
    }
#pragma unroll
    for (int j = 0; j < 4; ++j) {
        size_t zr = (size_t)(row0 + 4 * kb + j) * 256;
        z[zr + ci * 32 + u]       = hfin[j];
        z[zr + 128 + ci * 32 + u] = cst[j];
    }
}

// ---------------------------------------------------------------------------
// Decoder: block = 512 thr (8 waves: P x cell x q-half), 32 rows = 2 groups,
// grid 256. Slot pipeline: A (cells 0,1) on group g, B (cells 2,3) on g^1.
// h-part MFMAs of the NEXT slot hoisted before the barrier (h wave-private).
// ---------------------------------------------------------------------------
__global__ __launch_bounds__(512, 2)
void dec_kernel(const unsigned short* __restrict__ Whi, const float* __restrict__ bias,
                const float* __restrict__ z, float* __restrict__ xhat)
{
    __shared__ __align__(16) unsigned short Ysh[2][2][16][72];      // [grp][par][row][feat]
    __shared__ __align__(16) unsigned short Msh[2][16][72];         // [grp][row][feat]
    __shared__ __align__(16) unsigned short Hsh[4][2][2][16][40];   // [cell][grp][par][row][unit]

    const int tid = threadIdx.x, w = tid >> 6, lane = tid & 63;
    const int P = w >> 2, cl = (w >> 1) & 1, q = w & 1;
    const int cell = P * 2 + cl;
    const int a = lane & 15, kb = lane >> 4, u = q * 16 + a;
    const int row0 = blockIdx.x * 32;

    bf8v WH[4][3];   // 12 frags = 48 VGPR, pinned
#pragma unroll
    for (int g = 0; g < 4; ++g)
#pragma unroll
        for (int ki = 0; ki < 3; ++ki)
            WH[g][ki] = *(const bf8v*)(Whi + (size_t)cell * 12288 + (2 * g + q) * 1536
                                       + ki * 512 + lane * 8);
    float bj[4];
#pragma unroll
    for (int g = 0; g < 4; ++g)
        bj[g] = bias[cell * 128 + g * 32 + u] * ((g == 2) ? 2.f * L2E : L2E);

    float cst[2][4];   // [group][j]
#pragma unroll
    for (int G = 0; G < 2; ++G)
#pragma unroll
        for (int j = 0; j < 4; ++j)
            cst[G][j] = z[(size_t)(row0 + G * 16 + 4 * kb + j) * 256 + 128 + cell * 32 + u];

    {   // h-init -> parity-1: 4 cells x 32 rows x 32 units / 512 thr = 8 each
        int ct = tid >> 7, rem = tid & 127, rr = rem >> 2, u8 = (rem & 3) * 8;
        const float* src = z + (size_t)(row0 + rr) * 256 + ct * 32 + u8;
#pragma unroll
        for (int e = 0; e < 8; ++e)
            Hsh[ct][rr >> 4][1][rr & 15][u8 + e] = rne_bf16(src[e]);
    }
    __syncthreads();

    f4v accp[4];
    // h-part precompute for the wave's NEXT work item (wave-private h)
    auto hpart = [&](int G, int rpar) {
        bf8v hh = *(const bf8v*)&Hsh[cell][G][rpar][a][kb * 8];
#pragma unroll
        for (int g = 0; g < 4; ++g) {
            f4v t0 = (f4v){bj[g], bj[g], bj[g], bj[g]};
            accp[g] = mfma_bf16(hh, WH[g][2], t0);
        }
    };
    // post-barrier finish: V-read -> 8 MFMA -> lstm -> writes
    auto finish = [&](int G, int t, bool isA, bool hasV) {
        if (hasV) {
            const unsigned short (*Vh)[72] = isA ? Ysh[G][(t - 1) & 1] : Msh[G];
            bf8v vh0 = *(const bf8v*)&Vh[a][kb * 8];
            bf8v vh1 = *(const bf8v*)&Vh[a][32 + kb * 8];
#pragma unroll
            for (int g = 0; g < 4; ++g) {
                accp[g] = mfma_bf16(vh0, WH[g][0], accp[g]);
                accp[g] = mfma_bf16(vh1, WH[g][1], accp[g]);
            }
        }
#pragma unroll
        for (int j = 0; j < 4; ++j) {
            float hv = lstm_one(accp[0][j], accp[1][j], accp[2][j], accp[3][j], cst[G][j]);
            unsigned short hp = rne_bf16(hv);
            int r = 4 * kb + j;
            Hsh[cell][G][t & 1][r][u] = hp;
            if (isA) {
                Msh[G][r][cl * 32 + u] = hp;
            } else {
                Ysh[G][t & 1][r][cl * 32 + u] = hp;
                xhat[((size_t)(row0 + G * 16 + r) * Tn + t) * Fn + cl * 32 + u] = hv;
            }
        }
    };

    hpart(0, 1);   // prologue: both A and B first work item is G0 step 0
    for (int t = 0; t < Tn; ++t) {
        PINW(WH);
        // slot even: A on (G0,t); B on (G1,t-1)
        if (P == 0) { finish(0, t, true, t > 0);       hpart(1, (t - 1) & 1); }
        else        { if (t > 0) finish(1, t - 1, false, true); hpart(0, (t - 1) & 1); }
        lds_barrier();
        // slot odd: A on (G1,t); B on (G0,t)
        if (P == 0) { finish(1, t, true, t > 0);       hpart(0, t & 1); }
        else        { finish(0, t, false, true);       hpart(1, (t & 1) ^ 1); }
        lds_barrier();
    }
    if (P == 1) finish(1, Tn - 1, false, true);   // epilogue: G1 last step
}

extern "C" void kernel_launch(void* const* d_in, const int* in_sizes, int n_in,
                              void* d_out, int out_size, void* d_ws, size_t ws_size,
                              hipStream_t stream) {
    const float* x    = (const float*)d_in[0];
    const float* h0   = (const float*)d_in[1];
    const float* c0   = (const float*)d_in[2];
    const float* eWih = (const float*)d_in[3];
    const float* eWhh = (const float*)d_in[4];
    const float* eb   = (const float*)d_in[5];
    const float* dWih = (const float*)d_in[6];
    const float* dWhh = (const float*)d_in[7];
    const float* db   = (const float*)d_in[8];

    float* out = (float*)d_out;
    unsigned short* xs1h = (unsigned short*)d_out;          // [T,B,64] bf16 plane
    float* zb = out + (size_t)XHAT_ELEMS;                   // [B,256] latent
    unsigned short* wsb = (unsigned short*)d_ws;            // weight fragments

    hipLaunchKernelGGL(prep_kernel, dim3(48), dim3(256), 0, stream,
                       eWih, eWhh, dWih, dWhh, wsb);
    // encoder layer 0: x -> xs1 plane + z slots 0,1
    hipLaunchKernelGGL((enc_kernel<1>), dim3(Bn / 16), dim3(256), 0, stream,
                       x, (const unsigned short*)nullptr,
                       h0, c0, wsb, eb, 0, xs1h, zb);
    // encoder layer 1: xs1 plane -> z slots 2,3
    hipLaunchKernelGGL((enc_kernel<0>), dim3(Bn / 16), dim3(256), 0, stream,
                       (const float*)nullptr, xs1h,
                       h0, c0, wsb, eb, 1, (unsigned short*)nullptr, zb);
    // decoder: z -> x_hat (overwrites xs1 region)
    hipLaunchKernelGGL(dec_kernel, dim3(Bn / 32), dim3(512), 0, stream,
                       wsb + 98304, db, zb, out);
}